// Round 11
// baseline (114.565 us; speedup 1.0000x reference)
//
#include <hip/hip_runtime.h>
#include <math.h>

#define NB 128
#define NN 16
#define MM 32
#define DD 128
#define NACT 8
#define HH 64

// ---- static device scratch; every element rewritten by k_main each call ----
#define WS_W  0                     // weight  [128][256]
#define WS_WO 32768                 // weight_o[128][512]
#define WS_P  98304                 // P  = avact@W1a [128][16][64]
#define WS_V  229376                // V  = diff @W1a [128][16][64]
#define WS_PO 360448                // Po = avo  @W1b [128][32][64]
#define WS_FLOATS 622592            // ~2.5 MB

__device__ float g_ws[WS_FLOATS];

__device__ __forceinline__ float4 tanh4(float4 v) {
    float4 r; r.x = tanhf(v.x); r.y = tanhf(v.y); r.z = tanhf(v.z); r.w = tanhf(v.w); return r;
}
__device__ __forceinline__ void fma4(float4& a, float s, const float4& w) {
    a.x += s * w.x; a.y += s * w.y; a.z += s * w.z; a.w += s * w.w;
}

// grid 512 = 4 units x 128 batches, 512 thr (8 waves). Co-resident blocks
// (bid, bid+256) are units {0,2} or {1,3} -> phase diversity per CU.
// LDS max 13200 floats (52.8 KB) -> 2 blocks/CU, 16 waves/CU.
#define A_ST 0
#define A_Q  2112
#define A_K  4224
#define A2_AA 2112
#define A2_DF 4224
#define A2_AC 6336
#define A2_PO 6464
#define B_ST  0
#define B_QO  2112
#define B_STO 4224
#define B_KOT 8448
#define B_WO  12672
#define B2_STO 0
#define B2_AVO 4224
#define B2_AO  8448

__launch_bounds__(512, 2)
__global__ void k_main(const float* __restrict__ states,   const float* __restrict__ policies,
                       const float* __restrict__ actions,  const float* __restrict__ states_o,
                       const float* __restrict__ actions_o,
                       const float* __restrict__ Wq,  const float* __restrict__ Wk,
                       const float* __restrict__ Wv,  const float* __restrict__ Wqo,
                       const float* __restrict__ Wko, const float* __restrict__ Wvo,
                       const float* __restrict__ W1,  float* __restrict__ out) {
    __shared__ float sm[13200];
    const int unit = blockIdx.x >> 7;
    const int b = blockIdx.x & 127;
    const int t = threadIdx.x;
    const int row = t >> 5, c4 = (t & 31) * 4;
    const float scale = 0.08838834764831845f;   // 1/sqrt(128)

    if (unit == 0) {
        // ---------------- A1: q,k -> score -> softmax(in-reg) -> w ----------------
        *(float4*)&sm[A_ST + row * 132 + c4] = *(const float4*)(states + b * 2048 + row * 128 + c4);
        __syncthreads();
        {
            float4 q = {0,0,0,0}, k = {0,0,0,0};
            #pragma unroll 8
            for (int kk = 0; kk < DD; ++kk) {
                float x = sm[A_ST + row * 132 + kk];
                fma4(q, x, *(const float4*)(Wq + kk * 128 + c4));
                fma4(k, x, *(const float4*)(Wk + kk * 128 + c4));
            }
            *(float4*)&sm[A_Q + row * 132 + c4] = q;
            *(float4*)&sm[A_K + row * 132 + c4] = k;
        }
        __syncthreads();
        if (t < 256) {
            int i = t >> 4, j = t & 15;
            float acc = 0.f;
            #pragma unroll 8
            for (int d = 0; d < DD; ++d) acc += sm[A_Q + i * 132 + d] * sm[A_K + j * 132 + d];
            acc *= scale;
            float mx = acc;
            #pragma unroll
            for (int msk = 8; msk >= 1; msk >>= 1) mx = fmaxf(mx, __shfl_xor(mx, msk, 16));
            float e = expf(acc - mx);
            float sum = e;
            #pragma unroll
            for (int msk = 8; msk >= 1; msk >>= 1) sum += __shfl_xor(sum, msk, 16);
            float wv = e / sum;
            out[NB * 256 + b * 256 + t] = wv;
            g_ws[WS_W + b * 256 + t] = wv;
        }
    } else if (unit == 1) {
        // ---------------- A2: avact/diff -> P = avact@W1a, V = diff@W1a ----------------
        *(float4*)&sm[A_ST + row * 132 + c4] = *(const float4*)(states + b * 2048 + row * 128 + c4);
        if (t < 128) sm[A2_AC + t] = actions [b * 128 + t];
        else if (t < 256) sm[A2_PO + (t - 128)] = policies[b * 128 + (t - 128)];
        __syncthreads();
        {
            float4 a = {0,0,0,0};
            #pragma unroll 8
            for (int kk = 0; kk < DD; ++kk)
                fma4(a, sm[A_ST + row * 132 + kk], *(const float4*)(Wv + kk * 128 + c4));
            float4 aa = a, ap = a;
            #pragma unroll
            for (int k = 0; k < NACT; ++k) {
                float4 wv = *(const float4*)(Wv + (DD + k) * 128 + c4);
                fma4(aa, sm[A2_AC + row * 8 + k], wv);
                fma4(ap, sm[A2_PO + row * 8 + k], wv);
            }
            aa = tanh4(aa); ap = tanh4(ap);
            float4 df; df.x = ap.x - aa.x; df.y = ap.y - aa.y; df.z = ap.z - aa.z; df.w = ap.w - aa.w;
            *(float4*)&sm[A2_AA + row * 132 + c4] = aa;
            *(float4*)&sm[A2_DF + row * 132 + c4] = df;
        }
        __syncthreads();
        {
            // t<256: P from avact; t>=256: V from diff (wave-uniform split)
            int tt = t & 255, i = tt >> 4, h4 = (tt & 15) * 4;
            const float* src = (t < 256) ? sm + A2_AA : sm + A2_DF;
            float* dst = (t < 256) ? g_ws + WS_P + b * 1024 : g_ws + WS_V + b * 1024;
            float4 acc = {0,0,0,0};
            #pragma unroll 8
            for (int kk = 0; kk < DD; ++kk)
                fma4(acc, src[i * 132 + kk], *(const float4*)(W1 + kk * HH + h4));
            *(float4*)(dst + i * 64 + h4) = acc;
        }
    } else if (unit == 2) {
        // ---------------- B1: qo,ko -> score_o -> softmax_o -> wo ----------------
        *(float4*)&sm[B_ST + row * 132 + c4] = *(const float4*)(states + b * 2048 + row * 128 + c4);
        #pragma unroll
        for (int u = 0; u < 2; ++u) {
            int f = t + u * 512, r = f >> 5, cc = (f & 31) * 4;
            *(float4*)&sm[B_STO + r * 132 + cc] = *(const float4*)(states_o + b * 4096 + r * 128 + cc);
        }
        __syncthreads();
        {
            float4 g = {0,0,0,0}, o0 = {0,0,0,0}, o1 = {0,0,0,0};
            #pragma unroll 4
            for (int kk = 0; kk < DD; ++kk) {
                float xs = sm[B_ST  + row * 132 + kk];
                float x0 = sm[B_STO + row * 132 + kk];
                float x1 = sm[B_STO + (row + 16) * 132 + kk];
                float4 wq = *(const float4*)(Wqo + kk * 128 + c4);
                float4 wk = *(const float4*)(Wko + kk * 128 + c4);
                fma4(g, xs, wq); fma4(o0, x0, wk); fma4(o1, x1, wk);
            }
            *(float4*)&sm[B_QO + row * 132 + c4] = g;
            sm[B_KOT + (c4+0)*33 + row] = o0.x; sm[B_KOT + (c4+1)*33 + row] = o0.y;
            sm[B_KOT + (c4+2)*33 + row] = o0.z; sm[B_KOT + (c4+3)*33 + row] = o0.w;
            sm[B_KOT + (c4+0)*33 + row+16] = o1.x; sm[B_KOT + (c4+1)*33 + row+16] = o1.y;
            sm[B_KOT + (c4+2)*33 + row+16] = o1.z; sm[B_KOT + (c4+3)*33 + row+16] = o1.w;
        }
        __syncthreads();
        {
            int i = t >> 5, m = t & 31;
            float acc = 0.f;
            #pragma unroll 8
            for (int d = 0; d < DD; ++d) acc += sm[B_QO + i * 132 + d] * sm[B_KOT + d * 33 + m];
            sm[B_WO + i * 33 + m] = acc * scale;
        }
        __syncthreads();
        {
            // softmax over i per column m: map (m = t>>4, i = t&15) -> 16-lane groups
            int m = t >> 4, i = t & 15;
            float x = sm[B_WO + i * 33 + m];
            float mx = x;
            #pragma unroll
            for (int msk = 8; msk >= 1; msk >>= 1) mx = fmaxf(mx, __shfl_xor(mx, msk, 16));
            float e = expf(x - mx);
            float sum = e;
            #pragma unroll
            for (int msk = 8; msk >= 1; msk >>= 1) sum += __shfl_xor(sum, msk, 16);
            sm[B_WO + i * 33 + m] = e / sum;
        }
        __syncthreads();
        {
            float wv = sm[B_WO + (t >> 5) * 33 + (t & 31)];
            out[2 * NB * 256 + b * 512 + t] = wv;
            g_ws[WS_WO + b * 512 + t] = wv;
        }
    } else {
        // ---------------- B2: avo -> Po = avo@W1b ----------------
        #pragma unroll
        for (int u = 0; u < 2; ++u) {
            int f = t + u * 512, r = f >> 5, cc = (f & 31) * 4;
            *(float4*)&sm[B2_STO + r * 132 + cc] = *(const float4*)(states_o + b * 4096 + r * 128 + cc);
        }
        if (t < 256) sm[B2_AO + t] = actions_o[b * 256 + t];
        __syncthreads();
        {
            float4 v0 = {0,0,0,0}, v1 = {0,0,0,0};
            #pragma unroll 8
            for (int kk = 0; kk < DD; ++kk) {
                float4 wv = *(const float4*)(Wvo + kk * 128 + c4);
                fma4(v0, sm[B2_STO + row * 132 + kk], wv);
                fma4(v1, sm[B2_STO + (row + 16) * 132 + kk], wv);
            }
            #pragma unroll
            for (int k = 0; k < NACT; ++k) {
                float4 wv = *(const float4*)(Wvo + (DD + k) * 128 + c4);
                fma4(v0, sm[B2_AO + row * 8 + k], wv);
                fma4(v1, sm[B2_AO + (row + 16) * 8 + k], wv);
            }
            *(float4*)&sm[B2_AVO + row * 132 + c4]        = tanh4(v0);
            *(float4*)&sm[B2_AVO + (row + 16) * 132 + c4] = tanh4(v1);
        }
        __syncthreads();
        {
            int r = t >> 4, h4 = (t & 15) * 4;
            float4 acc = {0,0,0,0};
            #pragma unroll 8
            for (int kk = 0; kk < DD; ++kk)
                fma4(acc, sm[B2_AVO + r * 132 + kk], *(const float4*)(W1 + (DD + kk) * HH + h4));
            *(float4*)(g_ws + WS_PO + b * 2048 + r * 64 + h4) = acc;
        }
    }
}

// grid 128: U = w@P + wo@Po; value[i,j] = sum_h lrelu(U[i,h] + w[i,j] V[j,h]) W2[h]
__launch_bounds__(256, 2)
__global__ void k_fin(const float* __restrict__ W2, float* __restrict__ out) {
    __shared__ float s_w [16 * 17];
    __shared__ float s_wo[16 * 33];
    __shared__ float s_P [16 * 64];
    __shared__ float s_Po[32 * 64];
    __shared__ float s_V [16 * 68];
    __shared__ float s_U [16 * 68];
    __shared__ float s_W2[HH];
    const int b = blockIdx.x, t = threadIdx.x;

    s_w[(t >> 4) * 17 + (t & 15)] = g_ws[WS_W + b * 256 + t];
    s_wo[(t >> 5) * 33 + (t & 31)] = g_ws[WS_WO + b * 512 + t];
    s_wo[((t + 256) >> 5) * 33 + (t & 31)] = g_ws[WS_WO + b * 512 + 256 + t];
    ((float4*)s_P)[t] = ((const float4*)(g_ws + WS_P + b * 1024))[t];
    ((float4*)s_Po)[t] = ((const float4*)(g_ws + WS_PO + b * 2048))[t];
    ((float4*)s_Po)[t + 256] = ((const float4*)(g_ws + WS_PO + b * 2048))[t + 256];
    #pragma unroll
    for (int u = 0; u < 4; ++u) {
        int idx = t + u * 256;
        s_V[(idx >> 6) * 68 + (idx & 63)] = g_ws[WS_V + b * 1024 + idx];
    }
    if (t < HH) s_W2[t] = W2[t];
    __syncthreads();

    {
        int i = t >> 4, h4 = (t & 15) * 4;
        float4 u = {0,0,0,0};
        #pragma unroll
        for (int k = 0; k < NN; ++k) fma4(u, s_w[i * 17 + k], *(const float4*)&s_P[k * 64 + h4]);
        #pragma unroll
        for (int m = 0; m < MM; ++m) fma4(u, s_wo[i * 33 + m], *(const float4*)&s_Po[m * 64 + h4]);
        *(float4*)&s_U[i * 68 + h4] = u;
    }
    __syncthreads();

    {
        int i = t >> 4, j = t & 15;
        float wij = s_w[i * 17 + j];
        float acc = 0.f;
        #pragma unroll
        for (int h = 0; h < HH; ++h) {
            float x = s_U[i * 68 + h] + wij * s_V[j * 68 + h];
            x = (x > 0.f) ? x : 0.01f * x;
            acc += x * s_W2[h];
        }
        out[b * 256 + t] = acc;
    }
}

extern "C" void kernel_launch(void* const* d_in, const int* in_sizes, int n_in,
                              void* d_out, int out_size, void* d_ws, size_t ws_size,
                              hipStream_t stream) {
    const float* states    = (const float*)d_in[0];
    const float* policies  = (const float*)d_in[1];
    const float* actions   = (const float*)d_in[2];
    const float* states_o  = (const float*)d_in[3];
    const float* actions_o = (const float*)d_in[4];
    const float* Wk        = (const float*)d_in[5];
    const float* Wq        = (const float*)d_in[6];
    const float* Wv        = (const float*)d_in[7];
    const float* Wk_o      = (const float*)d_in[8];
    const float* Wq_o      = (const float*)d_in[9];
    const float* Wv_o      = (const float*)d_in[10];
    const float* W1        = (const float*)d_in[11];
    const float* W2        = (const float*)d_in[12];
    float* out = (float*)d_out;

    hipLaunchKernelGGL(k_main, dim3(512), dim3(512), 0, stream,
                       states, policies, actions, states_o, actions_o,
                       Wq, Wk, Wv, Wq_o, Wk_o, Wv_o, W1, out);
    hipLaunchKernelGGL(k_fin, dim3(128), dim3(256), 0, stream, W2, out);
}

// Round 13
// 104.413 us; speedup vs baseline: 1.0972x; 1.0972x over previous
//
#include <hip/hip_runtime.h>
#include <math.h>

#define NB 128
#define NN 16
#define MM 32
#define DD 128
#define NACT 8
#define HH 64

// ---- static device scratch; every element rewritten by k_main each call ----
#define WS_W  0                     // weight  [128][256]
#define WS_WO 32768                 // weight_o[128][512]
#define WS_P  98304                 // P  = avact@W1a [128][16][64]
#define WS_V  229376                // V  = diff @W1a [128][16][64]
#define WS_PO 360448                // Po = avo  @W1b [128][32][64]
#define WS_FLOATS 622592            // ~2.5 MB

__device__ float g_ws[WS_FLOATS];

__device__ __forceinline__ float4 tanh4(float4 v) {
    float4 r; r.x = tanhf(v.x); r.y = tanhf(v.y); r.z = tanhf(v.z); r.w = tanhf(v.w); return r;
}
__device__ __forceinline__ void fma4(float4& a, float s, const float4& w) {
    a.x += s * w.x; a.y += s * w.y; a.z += s * w.z; a.w += s * w.w;
}

// grid 512 = 4 units x 128 batches, 256 thr. Co-resident blocks are different
// units -> phase diversity per CU. LDS max 13200 floats (52.8 KB) -> 2 blocks/CU.
__launch_bounds__(256, 2)
__global__ void k_main(const float* __restrict__ states,   const float* __restrict__ policies,
                       const float* __restrict__ actions,  const float* __restrict__ states_o,
                       const float* __restrict__ actions_o,
                       const float* __restrict__ Wq,  const float* __restrict__ Wk,
                       const float* __restrict__ Wv,  const float* __restrict__ Wqo,
                       const float* __restrict__ Wko, const float* __restrict__ Wvo,
                       const float* __restrict__ W1,  float* __restrict__ out) {
    __shared__ float sm[13200];
    const int unit = blockIdx.x >> 7;
    const int b = blockIdx.x & 127;
    const int t = threadIdx.x;
    const float scale = 0.08838834764831845f;   // 1/sqrt(128)

    if (unit == 0) {
        // ---------------- A1: q,k -> score -> softmax(in-reg) -> w ----------------
        float* s_st = sm;            // [16][132]
        float* s_q  = sm + 2112;     // [16][132]
        float* s_k  = sm + 4224;     // [16][132]
        {
            int row = t >> 5, c4 = (t & 31) * 4;
            *(float4*)&s_st[row * 132 + c4] = *(const float4*)(states + b * 2048 + row * 128 + c4);
            int t2 = t + 256, row2 = t2 >> 5, c42 = (t2 & 31) * 4;
            *(float4*)&s_st[row2 * 132 + c42] = *(const float4*)(states + b * 2048 + row2 * 128 + c42);
        }
        __syncthreads();
        {
            const int p = t >> 5, c4 = (t & 31) * 4;
            float4 q0 = {0,0,0,0}, q1 = {0,0,0,0}, k0 = {0,0,0,0}, k1 = {0,0,0,0};
            #pragma unroll 8
            for (int kk = 0; kk < DD; ++kk) {
                float x0 = s_st[(2 * p) * 132 + kk], x1 = s_st[(2 * p + 1) * 132 + kk];
                float4 wq = *(const float4*)(Wq + kk * 128 + c4);
                float4 wk = *(const float4*)(Wk + kk * 128 + c4);
                fma4(q0, x0, wq); fma4(q1, x1, wq);
                fma4(k0, x0, wk); fma4(k1, x1, wk);
            }
            *(float4*)&s_q[(2 * p) * 132 + c4] = q0; *(float4*)&s_q[(2 * p + 1) * 132 + c4] = q1;
            *(float4*)&s_k[(2 * p) * 132 + c4] = k0; *(float4*)&s_k[(2 * p + 1) * 132 + c4] = k1;
        }
        __syncthreads();
        {
            // score + in-register softmax over j (16-lane groups), fused
            int i = t >> 4, j = t & 15;
            float acc = 0.f;
            #pragma unroll 8
            for (int d = 0; d < DD; ++d) acc += s_q[i * 132 + d] * s_k[j * 132 + d];
            acc *= scale;
            float mx = acc;
            #pragma unroll
            for (int msk = 8; msk >= 1; msk >>= 1) mx = fmaxf(mx, __shfl_xor(mx, msk, 16));
            float e = expf(acc - mx);
            float sum = e;
            #pragma unroll
            for (int msk = 8; msk >= 1; msk >>= 1) sum += __shfl_xor(sum, msk, 16);
            float wv = e / sum;
            out[NB * 256 + b * 256 + t] = wv;
            g_ws[WS_W + b * 256 + t] = wv;
        }
    } else if (unit == 1) {
        // ---------------- A2: avact/diff -> P = avact@W1a, V = diff@W1a ----------------
        float* s_st = sm;            // [16][132]
        float* s_aa = sm + 2112;     // [16][132]
        float* s_df = sm + 4224;     // [16][132]
        float* s_ac = sm + 6336;     // [16][8]
        float* s_po = sm + 6464;     // [16][8]
        {
            int row = t >> 5, c4 = (t & 31) * 4;
            *(float4*)&s_st[row * 132 + c4] = *(const float4*)(states + b * 2048 + row * 128 + c4);
            int t2 = t + 256, row2 = t2 >> 5, c42 = (t2 & 31) * 4;
            *(float4*)&s_st[row2 * 132 + c42] = *(const float4*)(states + b * 2048 + row2 * 128 + c42);
            if (t < 128) {
                s_ac[t] = actions [b * 128 + t];
                s_po[t] = policies[b * 128 + t];
            }
        }
        __syncthreads();
        {
            const int p = t >> 5, c4 = (t & 31) * 4;
            float4 a0 = {0,0,0,0}, a1 = {0,0,0,0};
            #pragma unroll 8
            for (int kk = 0; kk < DD; ++kk) {
                float4 wv = *(const float4*)(Wv + kk * 128 + c4);
                fma4(a0, s_st[(2 * p) * 132 + kk], wv);
                fma4(a1, s_st[(2 * p + 1) * 132 + kk], wv);
            }
            float4 aa0 = a0, aa1 = a1, ap0 = a0, ap1 = a1;
            #pragma unroll
            for (int k = 0; k < NACT; ++k) {
                float4 wv = *(const float4*)(Wv + (DD + k) * 128 + c4);
                fma4(aa0, s_ac[(2 * p) * 8 + k], wv); fma4(aa1, s_ac[(2 * p + 1) * 8 + k], wv);
                fma4(ap0, s_po[(2 * p) * 8 + k], wv); fma4(ap1, s_po[(2 * p + 1) * 8 + k], wv);
            }
            aa0 = tanh4(aa0); aa1 = tanh4(aa1); ap0 = tanh4(ap0); ap1 = tanh4(ap1);
            float4 d0, d1;
            d0.x = ap0.x - aa0.x; d0.y = ap0.y - aa0.y; d0.z = ap0.z - aa0.z; d0.w = ap0.w - aa0.w;
            d1.x = ap1.x - aa1.x; d1.y = ap1.y - aa1.y; d1.z = ap1.z - aa1.z; d1.w = ap1.w - aa1.w;
            *(float4*)&s_aa[(2 * p) * 132 + c4] = aa0; *(float4*)&s_aa[(2 * p + 1) * 132 + c4] = aa1;
            *(float4*)&s_df[(2 * p) * 132 + c4] = d0;  *(float4*)&s_df[(2 * p + 1) * 132 + c4] = d1;
        }
        __syncthreads();
        {
            const int i = t >> 4, h4 = (t & 15) * 4;
            float4 pa = {0,0,0,0}, va = {0,0,0,0};
            #pragma unroll 8
            for (int kk = 0; kk < DD; ++kk) {
                float4 w4 = *(const float4*)(W1 + kk * HH + h4);
                fma4(pa, s_aa[i * 132 + kk], w4);
                fma4(va, s_df[i * 132 + kk], w4);
            }
            *(float4*)(g_ws + WS_P + b * 1024 + i * 64 + h4) = pa;
            *(float4*)(g_ws + WS_V + b * 1024 + i * 64 + h4) = va;
        }
    } else if (unit == 2) {
        // ---------------- B1: qo,ko -> score_o -> softmax_o(in-reg) -> wo ----------------
        float* s_st  = sm;           // [16][132]
        float* s_qo  = sm + 2112;    // [16][132]
        float* s_sto = sm + 4224;    // [32][132]
        float* s_koT = sm + 8448;    // [128][33]
        float* s_wo  = sm + 12672;   // [16][33]
        {
            int row = t >> 5, c4 = (t & 31) * 4;
            *(float4*)&s_st[row * 132 + c4] = *(const float4*)(states + b * 2048 + row * 128 + c4);
            int t2 = t + 256, row2 = t2 >> 5, c42 = (t2 & 31) * 4;
            *(float4*)&s_st[row2 * 132 + c42] = *(const float4*)(states + b * 2048 + row2 * 128 + c42);
            #pragma unroll
            for (int u = 0; u < 4; ++u) {
                int f = t + u * 256, r = f >> 5, cc = (f & 31) * 4;
                *(float4*)&s_sto[r * 132 + cc] = *(const float4*)(states_o + b * 4096 + r * 128 + cc);
            }
        }
        __syncthreads();
        {
            const int p = t >> 5, c4 = (t & 31) * 4;
            float4 g0 = {0,0,0,0}, g1 = {0,0,0,0};
            float4 o0 = {0,0,0,0}, o1 = {0,0,0,0}, o2 = {0,0,0,0}, o3 = {0,0,0,0};
            #pragma unroll 8
            for (int kk = 0; kk < DD; ++kk) {
                float4 wq = *(const float4*)(Wqo + kk * 128 + c4);
                float4 wk = *(const float4*)(Wko + kk * 128 + c4);
                fma4(g0, s_st[(2 * p) * 132 + kk], wq);
                fma4(g1, s_st[(2 * p + 1) * 132 + kk], wq);
                fma4(o0, s_sto[(4 * p) * 132 + kk], wk);
                fma4(o1, s_sto[(4 * p + 1) * 132 + kk], wk);
                fma4(o2, s_sto[(4 * p + 2) * 132 + kk], wk);
                fma4(o3, s_sto[(4 * p + 3) * 132 + kk], wk);
            }
            *(float4*)&s_qo[(2 * p) * 132 + c4] = g0;
            *(float4*)&s_qo[(2 * p + 1) * 132 + c4] = g1;
            s_koT[(c4+0)*33 + 4*p]   = o0.x; s_koT[(c4+1)*33 + 4*p]   = o0.y; s_koT[(c4+2)*33 + 4*p]   = o0.z; s_koT[(c4+3)*33 + 4*p]   = o0.w;
            s_koT[(c4+0)*33 + 4*p+1] = o1.x; s_koT[(c4+1)*33 + 4*p+1] = o1.y; s_koT[(c4+2)*33 + 4*p+1] = o1.z; s_koT[(c4+3)*33 + 4*p+1] = o1.w;
            s_koT[(c4+0)*33 + 4*p+2] = o2.x; s_koT[(c4+1)*33 + 4*p+2] = o2.y; s_koT[(c4+2)*33 + 4*p+2] = o2.z; s_koT[(c4+3)*33 + 4*p+2] = o2.w;
            s_koT[(c4+0)*33 + 4*p+3] = o3.x; s_koT[(c4+1)*33 + 4*p+3] = o3.y; s_koT[(c4+2)*33 + 4*p+3] = o3.z; s_koT[(c4+3)*33 + 4*p+3] = o3.w;
        }
        __syncthreads();
        {
            int i = t >> 5, m = t & 31;
            float a0 = 0.f, a1 = 0.f;
            #pragma unroll 8
            for (int d = 0; d < DD; ++d) {
                float kv = s_koT[d * 33 + m];
                a0 += s_qo[i * 132 + d] * kv;
                a1 += s_qo[(i + 8) * 132 + d] * kv;
            }
            s_wo[i * 33 + m] = a0 * scale;
            s_wo[(i + 8) * 33 + m] = a1 * scale;
        }
        __syncthreads();
        {
            // softmax over i per column m, wave-parallel: groups of 16 lanes own one column
            int m = t >> 4, i = t & 15;
            float x = s_wo[i * 33 + m];
            float mx = x;
            #pragma unroll
            for (int msk = 8; msk >= 1; msk >>= 1) mx = fmaxf(mx, __shfl_xor(mx, msk, 16));
            float e = expf(x - mx);
            float sum = e;
            #pragma unroll
            for (int msk = 8; msk >= 1; msk >>= 1) sum += __shfl_xor(sum, msk, 16);
            float wv = e / sum;
            out[2 * NB * 256 + b * 512 + i * 32 + m] = wv;
            g_ws[WS_WO + b * 512 + i * 32 + m] = wv;
            // second half: columns m2 = 16 + (t>>4)
            int m2 = 16 + (t >> 4), i2 = t & 15;
            float x2 = s_wo[i2 * 33 + m2];
            float mx2 = x2;
            #pragma unroll
            for (int msk = 8; msk >= 1; msk >>= 1) mx2 = fmaxf(mx2, __shfl_xor(mx2, msk, 16));
            float e2 = expf(x2 - mx2);
            float sum2 = e2;
            #pragma unroll
            for (int msk = 8; msk >= 1; msk >>= 1) sum2 += __shfl_xor(sum2, msk, 16);
            float wv2 = e2 / sum2;
            out[2 * NB * 256 + b * 512 + i2 * 32 + m2] = wv2;
            g_ws[WS_WO + b * 512 + i2 * 32 + m2] = wv2;
        }
    } else {
        // ---------------- B2: avo -> Po = avo@W1b ----------------
        float* s_sto = sm;           // [32][132]
        float* s_avo = sm + 4224;    // [32][132]
        float* s_ao  = sm + 8448;    // [32][8]
        {
            #pragma unroll
            for (int u = 0; u < 4; ++u) {
                int f = t + u * 256, r = f >> 5, cc = (f & 31) * 4;
                *(float4*)&s_sto[r * 132 + cc] = *(const float4*)(states_o + b * 4096 + r * 128 + cc);
            }
            s_ao[t] = actions_o[b * 256 + t];
        }
        __syncthreads();
        {
            const int p = t >> 5, c4 = (t & 31) * 4;
            float4 v0 = {0,0,0,0}, v1 = {0,0,0,0}, v2 = {0,0,0,0}, v3 = {0,0,0,0};
            #pragma unroll 8
            for (int kk = 0; kk < DD; ++kk) {
                float4 wv = *(const float4*)(Wvo + kk * 128 + c4);
                fma4(v0, s_sto[(4 * p) * 132 + kk], wv);
                fma4(v1, s_sto[(4 * p + 1) * 132 + kk], wv);
                fma4(v2, s_sto[(4 * p + 2) * 132 + kk], wv);
                fma4(v3, s_sto[(4 * p + 3) * 132 + kk], wv);
            }
            #pragma unroll
            for (int k = 0; k < NACT; ++k) {
                float4 wv = *(const float4*)(Wvo + (DD + k) * 128 + c4);
                fma4(v0, s_ao[(4 * p) * 8 + k], wv);
                fma4(v1, s_ao[(4 * p + 1) * 8 + k], wv);
                fma4(v2, s_ao[(4 * p + 2) * 8 + k], wv);
                fma4(v3, s_ao[(4 * p + 3) * 8 + k], wv);
            }
            *(float4*)&s_avo[(4 * p) * 132 + c4]     = tanh4(v0);
            *(float4*)&s_avo[(4 * p + 1) * 132 + c4] = tanh4(v1);
            *(float4*)&s_avo[(4 * p + 2) * 132 + c4] = tanh4(v2);
            *(float4*)&s_avo[(4 * p + 3) * 132 + c4] = tanh4(v3);
        }
        __syncthreads();
        {
            const int r = t >> 4, h4 = (t & 15) * 4;
            float4 p0 = {0,0,0,0}, p1 = {0,0,0,0};
            #pragma unroll 8
            for (int kk = 0; kk < DD; ++kk) {
                float4 w4 = *(const float4*)(W1 + (DD + kk) * HH + h4);
                fma4(p0, s_avo[r * 132 + kk], w4);
                fma4(p1, s_avo[(r + 16) * 132 + kk], w4);
            }
            *(float4*)(g_ws + WS_PO + b * 2048 + r * 64 + h4) = p0;
            *(float4*)(g_ws + WS_PO + b * 2048 + (r + 16) * 64 + h4) = p1;
        }
    }
}

// grid 128: U = w@P + wo@Po; value[i,j] = sum_h lrelu(U[i,h] + w[i,j] V[j,h]) W2[h]
__launch_bounds__(256, 2)
__global__ void k_fin(const float* __restrict__ W2, float* __restrict__ out) {
    __shared__ float s_w [16 * 17];
    __shared__ float s_wo[16 * 33];
    __shared__ float s_P [16 * 64];
    __shared__ float s_Po[32 * 64];
    __shared__ float s_V [16 * 68];
    __shared__ float s_U [16 * 68];
    __shared__ float s_W2[HH];
    const int b = blockIdx.x, t = threadIdx.x;

    s_w[(t >> 4) * 17 + (t & 15)] = g_ws[WS_W + b * 256 + t];
    s_wo[(t >> 5) * 33 + (t & 31)] = g_ws[WS_WO + b * 512 + t];
    s_wo[((t + 256) >> 5) * 33 + (t & 31)] = g_ws[WS_WO + b * 512 + 256 + t];
    ((float4*)s_P)[t] = ((const float4*)(g_ws + WS_P + b * 1024))[t];
    ((float4*)s_Po)[t] = ((const float4*)(g_ws + WS_PO + b * 2048))[t];
    ((float4*)s_Po)[t + 256] = ((const float4*)(g_ws + WS_PO + b * 2048))[t + 256];
    #pragma unroll
    for (int u = 0; u < 4; ++u) {
        int idx = t + u * 256;
        s_V[(idx >> 6) * 68 + (idx & 63)] = g_ws[WS_V + b * 1024 + idx];
    }
    if (t < HH) s_W2[t] = W2[t];
    __syncthreads();

    {
        int i = t >> 4, h4 = (t & 15) * 4;
        float4 u = {0,0,0,0};
        #pragma unroll
        for (int k = 0; k < NN; ++k) fma4(u, s_w[i * 17 + k], *(const float4*)&s_P[k * 64 + h4]);
        #pragma unroll
        for (int m = 0; m < MM; ++m) fma4(u, s_wo[i * 33 + m], *(const float4*)&s_Po[m * 64 + h4]);
        *(float4*)&s_U[i * 68 + h4] = u;
    }
    __syncthreads();

    {
        int i = t >> 4, j = t & 15;
        float wij = s_w[i * 17 + j];
        float acc = 0.f;
        #pragma unroll
        for (int h = 0; h < HH; ++h) {
            float x = s_U[i * 68 + h] + wij * s_V[j * 68 + h];
            x = (x > 0.f) ? x : 0.01f * x;
            acc += x * s_W2[h];
        }
        out[b * 256 + t] = acc;
    }
}

extern "C" void kernel_launch(void* const* d_in, const int* in_sizes, int n_in,
                              void* d_out, int out_size, void* d_ws, size_t ws_size,
                              hipStream_t stream) {
    const float* states    = (const float*)d_in[0];
    const float* policies  = (const float*)d_in[1];
    const float* actions   = (const float*)d_in[2];
    const float* states_o  = (const float*)d_in[3];
    const float* actions_o = (const float*)d_in[4];
    const float* Wk        = (const float*)d_in[5];
    const float* Wq        = (const float*)d_in[6];
    const float* Wv        = (const float*)d_in[7];
    const float* Wk_o      = (const float*)d_in[8];
    const float* Wq_o      = (const float*)d_in[9];
    const float* Wv_o      = (const float*)d_in[10];
    const float* W1        = (const float*)d_in[11];
    const float* W2        = (const float*)d_in[12];
    float* out = (float*)d_out;

    hipLaunchKernelGGL(k_main, dim3(512), dim3(256), 0, stream,
                       states, policies, actions, states_o, actions_o,
                       Wq, Wk, Wv, Wq_o, Wk_o, Wv_o, W1, out);
    hipLaunchKernelGGL(k_fin, dim3(128), dim3(256), 0, stream, W2, out);
}